// Round 5
// baseline (1728.340 us; speedup 1.0000x reference)
//
#include <hip/hip_runtime.h>
#include <math.h>

#define BB 8
#define NN 8192
#define CC 64
#define FE 32
#define KN 16
#define CP3 67

// Device-global scratch (module .bss). All bytes written every launch before read.
__device__ float g_wsf[128];                 // scale[64], shift[64]
__device__ float g_feat0[BB * NN * FE];      // 8 MB
__device__ int   g_idx[BB * NN * KN];        // 4 MB

// ---------------- kernel 1: BN stats -> scale/shift ----------------
__global__ __launch_bounds__(256) void k_bnstats(const float* __restrict__ feat,
        const float* __restrict__ gamma, const float* __restrict__ beta) {
    int c = blockIdx.x;
    int tid = threadIdx.x;
    double s = 0.0, s2 = 0.0;
    for (int b = 0; b < BB; ++b) {
        const float* p = feat + ((size_t)(b * CC + c)) * NN;
        for (int n = tid; n < NN; n += 256) {
            double v = (double)p[n];
            s += v; s2 += v * v;
        }
    }
    __shared__ double sh[256], sh2[256];
    sh[tid] = s; sh2[tid] = s2;
    __syncthreads();
    for (int off = 128; off > 0; off >>= 1) {
        if (tid < off) { sh[tid] += sh[tid + off]; sh2[tid] += sh2[tid + off]; }
        __syncthreads();
    }
    if (tid == 0) {
        double inv = 1.0 / (double)(BB * NN);
        double mean = sh[0] * inv;
        double var = sh2[0] * inv - mean * mean;
        float sc = gamma[c] * (float)(1.0 / sqrt(var + (double)1e-5f));
        g_wsf[c] = sc;                                  // scale
        g_wsf[64 + c] = beta[c] - sc * (float)mean;     // shift
    }
}

// ---------------- kernel 2: feat0 = Wg' * [feat;xyz] + bias0 ----------------
__global__ __launch_bounds__(256) void k_feat0(const float* __restrict__ feat,
        const float* __restrict__ xyz, const float* __restrict__ Wg) {
    __shared__ float wgs[CP3 * FE];  // [c][e]
    __shared__ float bias0[FE];
    int tid = threadIdx.x;
    for (int i = tid; i < CP3 * FE; i += 256) {
        int c = i >> 5, e = i & 31;
        float w = Wg[e * CP3 + c];
        if (c < CC) w *= g_wsf[c];
        wgs[c * FE + e] = w;
    }
    if (tid < FE) {
        float sacc = 0.f;
        for (int c = 0; c < CC; ++c) sacc = fmaf(Wg[tid * CP3 + c], g_wsf[64 + c], sacc);
        bias0[tid] = sacc;
    }
    __syncthreads();
    int b = blockIdx.x >> 5;
    int n = ((blockIdx.x & 31) << 8) + tid;
    const float* pz = xyz + ((size_t)(b * NN + n)) * 3;
    float x = pz[0], y = pz[1], z = pz[2];

    float acc[FE];
    #pragma unroll
    for (int e = 0; e < FE; ++e) acc[e] = bias0[e];
    const float* fp = feat + (size_t)b * CC * NN + n;
    for (int c = 0; c < CC; ++c) {
        float v = fp[(size_t)c * NN];
        const float4* w4 = (const float4*)(wgs + c * FE);
        #pragma unroll
        for (int e0 = 0; e0 < 8; ++e0) {
            float4 w = w4[e0];
            acc[e0 * 4 + 0] = fmaf(w.x, v, acc[e0 * 4 + 0]);
            acc[e0 * 4 + 1] = fmaf(w.y, v, acc[e0 * 4 + 1]);
            acc[e0 * 4 + 2] = fmaf(w.z, v, acc[e0 * 4 + 2]);
            acc[e0 * 4 + 3] = fmaf(w.w, v, acc[e0 * 4 + 3]);
        }
    }
    #pragma unroll
    for (int d = 0; d < 3; ++d) {
        float v = (d == 0) ? x : ((d == 1) ? y : z);
        const float4* w4 = (const float4*)(wgs + (CC + d) * FE);
        #pragma unroll
        for (int e0 = 0; e0 < 8; ++e0) {
            float4 w = w4[e0];
            acc[e0 * 4 + 0] = fmaf(w.x, v, acc[e0 * 4 + 0]);
            acc[e0 * 4 + 1] = fmaf(w.y, v, acc[e0 * 4 + 1]);
            acc[e0 * 4 + 2] = fmaf(w.z, v, acc[e0 * 4 + 2]);
            acc[e0 * 4 + 3] = fmaf(w.w, v, acc[e0 * 4 + 3]);
        }
    }
    float4* outp = (float4*)(g_feat0 + ((size_t)(b * NN + n)) * FE);
    #pragma unroll
    for (int e0 = 0; e0 < 8; ++e0)
        outp[e0] = make_float4(acc[e0 * 4 + 0], acc[e0 * 4 + 1], acc[e0 * 4 + 2], acc[e0 * 4 + 3]);
}

// ---------------- kernel 3: exact KNN, XLA-CPU (FPOpFusion::Fast) arithmetic ---
// Hypothesis H5: the reference npz was produced by XLA CPU, whose backend fuses
// every mul+add into FMA (FPOpFusion::Fast), ascending loop order:
//   xx   = fma(z,z, fma(y,y, x*x))
//   dot  = fma(zq,zm, fma(yq,ym, xq*xm))
//   dist = (xx_n - 2*dot) + xx_m        (sub->fma(-2,dot,xx_n) is bit-identical)
__device__ __forceinline__ float xla_xx(float x, float y, float z) {
    return __fmaf_rn(z, z, __fmaf_rn(y, y, __fmul_rn(x, x)));
}

__global__ __launch_bounds__(256) void k_knn(const float* __restrict__ xyz) {
    __shared__ float4 tile[256];
    __shared__ int eqbuf[256 * 16];
    int tid = threadIdx.x;
    int b = blockIdx.x >> 5;
    int q = ((blockIdx.x & 31) << 8) + tid;
    const float* pq = xyz + ((size_t)(b * NN + q)) * 3;
    float xq = pq[0], yq = pq[1], zq = pq[2];
    float xxq = xla_xx(xq, yq, zq);
    const float* bxyz = xyz + (size_t)b * NN * 3;

    float a[KN];
    #pragma unroll
    for (int i = 0; i < KN; ++i) a[i] = __builtin_inff();

    // pass 1: 16 smallest distance VALUES
    for (int t = 0; t < NN / 256; ++t) {
        int cid = t * 256 + tid;
        float cx = bxyz[cid * 3], cy = bxyz[cid * 3 + 1], cz = bxyz[cid * 3 + 2];
        float cxx = xla_xx(cx, cy, cz);
        __syncthreads();
        tile[tid] = make_float4(cx, cy, cz, cxx);
        __syncthreads();
        #pragma unroll 4
        for (int j = 0; j < 256; ++j) {
            float4 cc = tile[j];
            float dot = __fmaf_rn(zq, cc.z, __fmaf_rn(yq, cc.y, __fmul_rn(xq, cc.x)));
            float dist = __fadd_rn(__fmaf_rn(-2.f, dot, xxq), cc.w);
            if (dist < a[KN - 1]) {
                #pragma unroll
                for (int u = KN - 1; u >= 1; --u)
                    a[u] = fmaxf(a[u - 1], fminf(a[u], dist));
                a[0] = fminf(a[0], dist);
            }
        }
    }
    float thr = a[KN - 1];
    // pass 2: recover indices; stable (lower-index) tie semantics
    int cnt = 0, eqc = 0;
    int* myeq = eqbuf + tid * 16;
    int obase = (b * NN + q) * KN;
    for (int t = 0; t < NN / 256; ++t) {
        int cid = t * 256 + tid;
        float cx = bxyz[cid * 3], cy = bxyz[cid * 3 + 1], cz = bxyz[cid * 3 + 2];
        float cxx = xla_xx(cx, cy, cz);
        __syncthreads();
        tile[tid] = make_float4(cx, cy, cz, cxx);
        __syncthreads();
        #pragma unroll 4
        for (int j = 0; j < 256; ++j) {
            float4 cc = tile[j];
            float dot = __fmaf_rn(zq, cc.z, __fmaf_rn(yq, cc.y, __fmul_rn(xq, cc.x)));
            float dist = __fadd_rn(__fmaf_rn(-2.f, dot, xxq), cc.w);
            if (dist < thr) {
                if (cnt < KN) g_idx[obase + cnt] = t * 256 + j;
                cnt++;
            } else if (dist == thr) {
                if (eqc < 16) myeq[eqc] = t * 256 + j;
                eqc++;
            }
        }
    }
    int lim = eqc < 16 ? eqc : 16;
    for (int j2 = 0; j2 < lim && cnt < KN; ++j2) {
        g_idx[obase + cnt] = myeq[j2];
        cnt++;
    }
}

// ---------------- kernel 4: gather+max, rel, out = Wh' * rel ----------------
__global__ __launch_bounds__(256) void k_out(const float* __restrict__ Wh,
        float* __restrict__ out) {
    __shared__ float whs[CC * FE];
    int tid = threadIdx.x;
    for (int i = tid; i < CC * FE; i += 256) {
        int c = i >> 5, e = i & 31;
        float s = 0.f;
        #pragma unroll
        for (int m = 0; m < 4; ++m) s += Wh[c * 128 + m * 32 + e];
        whs[i] = s;
    }
    __syncthreads();
    int b = blockIdx.x >> 5;
    int n = ((blockIdx.x & 31) << 8) + tid;
    const int* ip = g_idx + (size_t)(b * NN + n) * KN;
    const float4* f0 = (const float4*)(g_feat0 + (size_t)b * NN * FE);
    float gmax[FE];
    #pragma unroll
    for (int e = 0; e < FE; ++e) gmax[e] = -__builtin_inff();
    for (int k = 0; k < KN; ++k) {
        int id = ip[k];
        const float4* row = f0 + id * 8;
        #pragma unroll
        for (int e0 = 0; e0 < 8; ++e0) {
            float4 v = row[e0];
            gmax[e0 * 4 + 0] = fmaxf(gmax[e0 * 4 + 0], v.x);
            gmax[e0 * 4 + 1] = fmaxf(gmax[e0 * 4 + 1], v.y);
            gmax[e0 * 4 + 2] = fmaxf(gmax[e0 * 4 + 2], v.z);
            gmax[e0 * 4 + 3] = fmaxf(gmax[e0 * 4 + 3], v.w);
        }
    }
    const float4* selfr = f0 + n * 8;
    float rel[FE];
    #pragma unroll
    for (int e0 = 0; e0 < 8; ++e0) {
        float4 v = selfr[e0];
        rel[e0 * 4 + 0] = gmax[e0 * 4 + 0] - v.x;
        rel[e0 * 4 + 1] = gmax[e0 * 4 + 1] - v.y;
        rel[e0 * 4 + 2] = gmax[e0 * 4 + 2] - v.z;
        rel[e0 * 4 + 3] = gmax[e0 * 4 + 3] - v.w;
    }
    float* op = out + (size_t)b * CC * NN + n;
    for (int c = 0; c < CC; ++c) {
        const float4* w4 = (const float4*)(whs + c * FE);
        float s = 0.f;
        #pragma unroll
        for (int e0 = 0; e0 < 8; ++e0) {
            float4 w = w4[e0];
            s = fmaf(w.x, rel[e0 * 4 + 0], s);
            s = fmaf(w.y, rel[e0 * 4 + 1], s);
            s = fmaf(w.z, rel[e0 * 4 + 2], s);
            s = fmaf(w.w, rel[e0 * 4 + 3], s);
        }
        op[(size_t)c * NN] = s;
    }
}

extern "C" void kernel_launch(void* const* d_in, const int* in_sizes, int n_in,
                              void* d_out, int out_size, void* d_ws, size_t ws_size,
                              hipStream_t stream) {
    const float* xyz   = (const float*)d_in[0];
    const float* feat  = (const float*)d_in[1];
    const float* gamma = (const float*)d_in[2];
    const float* beta  = (const float*)d_in[3];
    const float* Wg    = (const float*)d_in[4];
    const float* Wh    = (const float*)d_in[5];
    float* out = (float*)d_out;
    (void)d_ws; (void)ws_size;

    hipLaunchKernelGGL(k_bnstats, dim3(64),  dim3(256), 0, stream, feat, gamma, beta);
    hipLaunchKernelGGL(k_feat0,   dim3(256), dim3(256), 0, stream, feat, xyz, Wg);
    hipLaunchKernelGGL(k_knn,     dim3(256), dim3(256), 0, stream, xyz);
    hipLaunchKernelGGL(k_out,     dim3(256), dim3(256), 0, stream, Wh, out);
}

// Round 7
// 508.942 us; speedup vs baseline: 3.3959x; 3.3959x over previous
//
#include <hip/hip_runtime.h>
#include <math.h>

#define BB 8
#define NN 8192
#define CC 64
#define FE 32
#define KN 16
#define CP3 67
#define CAPB 256      // per-query candidate buffer (count-checked => exact)
#define TILE 512
#define NTILE (NN / TILE)

// Device-global scratch (module .bss). All bytes written every launch before read.
__device__ float g_wsf[128];                 // scale[64], shift[64]
__device__ float g_feat0[BB * NN * FE];      // 8 MB
__device__ int   g_idx[BB * NN * KN];        // 4 MB

// ---------------- kernel 1: BN stats -> scale/shift ----------------
__global__ __launch_bounds__(256) void k_bnstats(const float* __restrict__ feat,
        const float* __restrict__ gamma, const float* __restrict__ beta) {
    int c = blockIdx.x;
    int tid = threadIdx.x;
    double s = 0.0, s2 = 0.0;
    for (int b = 0; b < BB; ++b) {
        const float* p = feat + ((size_t)(b * CC + c)) * NN;
        for (int n = tid; n < NN; n += 256) {
            double v = (double)p[n];
            s += v; s2 += v * v;
        }
    }
    __shared__ double sh[256], sh2[256];
    sh[tid] = s; sh2[tid] = s2;
    __syncthreads();
    for (int off = 128; off > 0; off >>= 1) {
        if (tid < off) { sh[tid] += sh[tid + off]; sh2[tid] += sh2[tid + off]; }
        __syncthreads();
    }
    if (tid == 0) {
        double inv = 1.0 / (double)(BB * NN);
        double mean = sh[0] * inv;
        double var = sh2[0] * inv - mean * mean;
        float sc = gamma[c] * (float)(1.0 / sqrt(var + (double)1e-5f));
        g_wsf[c] = sc;                                  // scale
        g_wsf[64 + c] = beta[c] - sc * (float)mean;     // shift
    }
}

// ---------------- kernel 2: feat0 = Wg' * [feat;xyz] + bias0 ----------------
__global__ __launch_bounds__(256) void k_feat0(const float* __restrict__ feat,
        const float* __restrict__ xyz, const float* __restrict__ Wg) {
    __shared__ float wgs[CP3 * FE];  // [c][e]
    __shared__ float bias0[FE];
    int tid = threadIdx.x;
    for (int i = tid; i < CP3 * FE; i += 256) {
        int c = i >> 5, e = i & 31;
        float w = Wg[e * CP3 + c];
        if (c < CC) w *= g_wsf[c];
        wgs[c * FE + e] = w;
    }
    if (tid < FE) {
        float sacc = 0.f;
        for (int c = 0; c < CC; ++c) sacc = fmaf(Wg[tid * CP3 + c], g_wsf[64 + c], sacc);
        bias0[tid] = sacc;
    }
    __syncthreads();
    int b = blockIdx.x >> 5;
    int n = ((blockIdx.x & 31) << 8) + tid;
    const float* pz = xyz + ((size_t)(b * NN + n)) * 3;
    float x = pz[0], y = pz[1], z = pz[2];

    float acc[FE];
    #pragma unroll
    for (int e = 0; e < FE; ++e) acc[e] = bias0[e];
    const float* fp = feat + (size_t)b * CC * NN + n;
    for (int c = 0; c < CC; ++c) {
        float v = fp[(size_t)c * NN];
        const float4* w4 = (const float4*)(wgs + c * FE);
        #pragma unroll
        for (int e0 = 0; e0 < 8; ++e0) {
            float4 w = w4[e0];
            acc[e0 * 4 + 0] = fmaf(w.x, v, acc[e0 * 4 + 0]);
            acc[e0 * 4 + 1] = fmaf(w.y, v, acc[e0 * 4 + 1]);
            acc[e0 * 4 + 2] = fmaf(w.z, v, acc[e0 * 4 + 2]);
            acc[e0 * 4 + 3] = fmaf(w.w, v, acc[e0 * 4 + 3]);
        }
    }
    #pragma unroll
    for (int d = 0; d < 3; ++d) {
        float v = (d == 0) ? x : ((d == 1) ? y : z);
        const float4* w4 = (const float4*)(wgs + (CC + d) * FE);
        #pragma unroll
        for (int e0 = 0; e0 < 8; ++e0) {
            float4 w = w4[e0];
            acc[e0 * 4 + 0] = fmaf(w.x, v, acc[e0 * 4 + 0]);
            acc[e0 * 4 + 1] = fmaf(w.y, v, acc[e0 * 4 + 1]);
            acc[e0 * 4 + 2] = fmaf(w.z, v, acc[e0 * 4 + 2]);
            acc[e0 * 4 + 3] = fmaf(w.w, v, acc[e0 * 4 + 3]);
        }
    }
    float4* outp = (float4*)(g_feat0 + ((size_t)(b * NN + n)) * FE);
    #pragma unroll
    for (int e0 = 0; e0 < 8; ++e0)
        outp[e0] = make_float4(acc[e0 * 4 + 0], acc[e0 * 4 + 1], acc[e0 * 4 + 2], acc[e0 * 4 + 3]);
}

// ---------------- kernel 3: wave-cooperative exact KNN -------------------
// FROZEN reference arithmetic (verified R5, XLA-CPU FMA contraction):
//   xx   = fma(z,z, fma(y,y, x*x))
//   dot  = fma(zq,zm, fma(yq,ym, xq*xm))
//   dist = fadd( fma(-2, dot, xx_q), xx_m )
// One wave per query. Gate dist<=t0, buffer (key,idx); exactness by count
// check (16 <= cnt <= CAPB implies buffer contains the true top-16).
// Retry factors x2 / x0.5: count moves ~2.8x per step << 16x window width,
// so the [16,256] acceptance window cannot be jumped over (R6 bug: x4/x0.25
// stepped counts ~8x and could oscillate forever across the window).
__global__ __launch_bounds__(256) void k_knn(const float* __restrict__ xyz) {
    __shared__ float4 tilebuf[TILE];                    // 8 KB
    __shared__ unsigned long long pbuf[4 * CAPB];       // 8 KB
    int tid = threadIdx.x;
    int lane = tid & 63;
    int warp = tid >> 6;
    int q = blockIdx.x * 4 + warp;                      // 0..65535
    int b = q >> 13;
    int n = q & (NN - 1);
    const float* bxyz = xyz + (size_t)b * NN * 3;
    const float* pq = bxyz + (size_t)n * 3;
    float xq = pq[0], yq = pq[1], zq = pq[2];
    float xxq = __fmaf_rn(zq, zq, __fmaf_rn(yq, yq, __fmul_rn(xq, xq)));
    unsigned long long* mybuf = pbuf + warp * CAPB;
    unsigned long long lt = (1ull << lane) - 1ull;

    // analytic ~48-NN radius^2 estimate (geometric center of the [16,256]
    // acceptance window); correctness does not depend on it (count check).
    float t0 = 0.13f * __expf(xxq * (1.0f / 3.0f));
    if (t0 > 40.f) t0 = 40.f;
    bool done = false;
    int cnt = 0;

    for (int attempt = 0; attempt < 40; ++attempt) {
        if (!done) cnt = 0;
        for (int t = 0; t < NTILE; ++t) {
            __syncthreads();
            {   // stage 2 candidates per thread: float4{x,y,z,xx}
                int c0 = t * TILE + tid * 2;
                const float* p0 = bxyz + (size_t)c0 * 3;
                float ax = p0[0], ay = p0[1], az = p0[2];
                float bx = p0[3], by = p0[4], bz = p0[5];
                float axx = __fmaf_rn(az, az, __fmaf_rn(ay, ay, __fmul_rn(ax, ax)));
                float bxx = __fmaf_rn(bz, bz, __fmaf_rn(by, by, __fmul_rn(bx, bx)));
                tilebuf[tid * 2]     = make_float4(ax, ay, az, axx);
                tilebuf[tid * 2 + 1] = make_float4(bx, by, bz, bxx);
            }
            __syncthreads();
            if (done) continue;
            #pragma unroll
            for (int s = 0; s < TILE / 64; ++s) {
                float4 cc = tilebuf[s * 64 + lane];
                float dot = __fmaf_rn(zq, cc.z, __fmaf_rn(yq, cc.y, __fmul_rn(xq, cc.x)));
                float dist = __fadd_rn(__fmaf_rn(-2.f, dot, xxq), cc.w);
                bool pred = (dist <= t0);
                unsigned long long mask = __ballot(pred);
                int pos = cnt + __popcll(mask & lt);
                if (pred && pos < CAPB) {
                    int bb = __float_as_int(dist);
                    unsigned key = (unsigned)bb ^ (unsigned)((bb >> 31) | 0x80000000);
                    unsigned cand = (unsigned)(t * TILE + s * 64 + lane);
                    mybuf[pos] = ((unsigned long long)key << 32) | cand;
                }
                cnt += __popcll(mask);
            }
        }
        if (!done) {
            if (cnt >= KN && cnt <= CAPB) done = true;
            else t0 = (cnt < KN) ? t0 * 2.0f : t0 * 0.5f;
        }
        if (!__syncthreads_or(!done)) break;
    }
    if (cnt > CAPB) cnt = CAPB;   // unreachable safety

    // exact top-16 selection from mybuf[0..cnt)
    unsigned long long r0 = (lane < cnt)       ? mybuf[lane]       : ~0ull;
    unsigned long long r1 = (64 + lane < cnt)  ? mybuf[64 + lane]  : ~0ull;
    unsigned long long r2 = (128 + lane < cnt) ? mybuf[128 + lane] : ~0ull;
    unsigned long long r3 = (192 + lane < cnt) ? mybuf[192 + lane] : ~0ull;
    int obase = q * KN;
    for (int k = 0; k < KN; ++k) {
        unsigned long long m01 = r0 < r1 ? r0 : r1;
        unsigned long long m23 = r2 < r3 ? r2 : r3;
        unsigned long long m = m01 < m23 ? m01 : m23;
        #pragma unroll
        for (int off = 32; off >= 1; off >>= 1) {
            unsigned long long o = __shfl_xor(m, off, 64);
            if (o < m) m = o;
        }
        if (lane == 0) g_idx[obase + k] = (int)(m & 0xffffffffull);
        r0 = (r0 == m) ? ~0ull : r0;
        r1 = (r1 == m) ? ~0ull : r1;
        r2 = (r2 == m) ? ~0ull : r2;
        r3 = (r3 == m) ? ~0ull : r3;
    }
}

// ---------------- kernel 4: gather+max, rel, out = Wh' * rel ----------------
__global__ __launch_bounds__(256) void k_out(const float* __restrict__ Wh,
        float* __restrict__ out) {
    __shared__ float whs[CC * FE];
    int tid = threadIdx.x;
    for (int i = tid; i < CC * FE; i += 256) {
        int c = i >> 5, e = i & 31;
        float s = 0.f;
        #pragma unroll
        for (int m = 0; m < 4; ++m) s += Wh[c * 128 + m * 32 + e];
        whs[i] = s;
    }
    __syncthreads();
    int b = blockIdx.x >> 5;
    int n = ((blockIdx.x & 31) << 8) + tid;
    const int* ip = g_idx + (size_t)(b * NN + n) * KN;
    const float4* f0 = (const float4*)(g_feat0 + (size_t)b * NN * FE);
    float gmax[FE];
    #pragma unroll
    for (int e = 0; e < FE; ++e) gmax[e] = -__builtin_inff();
    for (int k = 0; k < KN; ++k) {
        int id = ip[k];
        const float4* row = f0 + (size_t)id * 8;
        #pragma unroll
        for (int e0 = 0; e0 < 8; ++e0) {
            float4 v = row[e0];
            gmax[e0 * 4 + 0] = fmaxf(gmax[e0 * 4 + 0], v.x);
            gmax[e0 * 4 + 1] = fmaxf(gmax[e0 * 4 + 1], v.y);
            gmax[e0 * 4 + 2] = fmaxf(gmax[e0 * 4 + 2], v.z);
            gmax[e0 * 4 + 3] = fmaxf(gmax[e0 * 4 + 3], v.w);
        }
    }
    const float4* selfr = f0 + (size_t)n * 8;
    float rel[FE];
    #pragma unroll
    for (int e0 = 0; e0 < 8; ++e0) {
        float4 v = selfr[e0];
        rel[e0 * 4 + 0] = gmax[e0 * 4 + 0] - v.x;
        rel[e0 * 4 + 1] = gmax[e0 * 4 + 1] - v.y;
        rel[e0 * 4 + 2] = gmax[e0 * 4 + 2] - v.z;
        rel[e0 * 4 + 3] = gmax[e0 * 4 + 3] - v.w;
    }
    float* op = out + (size_t)b * CC * NN + n;
    for (int c = 0; c < CC; ++c) {
        const float4* w4 = (const float4*)(whs + c * FE);
        float s = 0.f;
        #pragma unroll
        for (int e0 = 0; e0 < 8; ++e0) {
            float4 w = w4[e0];
            s = fmaf(w.x, rel[e0 * 4 + 0], s);
            s = fmaf(w.y, rel[e0 * 4 + 1], s);
            s = fmaf(w.z, rel[e0 * 4 + 2], s);
            s = fmaf(w.w, rel[e0 * 4 + 3], s);
        }
        op[(size_t)c * NN] = s;
    }
}

extern "C" void kernel_launch(void* const* d_in, const int* in_sizes, int n_in,
                              void* d_out, int out_size, void* d_ws, size_t ws_size,
                              hipStream_t stream) {
    const float* xyz   = (const float*)d_in[0];
    const float* feat  = (const float*)d_in[1];
    const float* gamma = (const float*)d_in[2];
    const float* beta  = (const float*)d_in[3];
    const float* Wg    = (const float*)d_in[4];
    const float* Wh    = (const float*)d_in[5];
    float* out = (float*)d_out;
    (void)d_ws; (void)ws_size;

    hipLaunchKernelGGL(k_bnstats, dim3(64),    dim3(256), 0, stream, feat, gamma, beta);
    hipLaunchKernelGGL(k_feat0,   dim3(256),   dim3(256), 0, stream, feat, xyz, Wg);
    hipLaunchKernelGGL(k_knn,     dim3(16384), dim3(256), 0, stream, xyz);
    hipLaunchKernelGGL(k_out,     dim3(256),   dim3(256), 0, stream, Wh, out);
}

// Round 9
// 376.753 us; speedup vs baseline: 4.5875x; 1.3509x over previous
//
#include <hip/hip_runtime.h>
#include <math.h>

#define BB 8
#define NN 8192
#define CC 64
#define FE 32
#define KN 16
#define CP3 67
#define TILE 512
#define NTILE (NN / TILE)
#define QPW 4                 // queries per wave
#define QPB 16                // queries per block (4 waves)
#define CAPQ 256              // per-query candidate stack (count-checked => exact)

// Device-global scratch (module .bss). All bytes written every launch before read.
__device__ float g_wsf[128];                 // scale[64], shift[64]
__device__ float g_feat0[BB * NN * FE];      // 8 MB
__device__ int   g_idx[BB * NN * KN];        // 4 MB

// ---------------- kernel 1: BN stats -> scale/shift ----------------
__global__ __launch_bounds__(1024) void k_bnstats(const float* __restrict__ feat,
        const float* __restrict__ gamma, const float* __restrict__ beta) {
    int c = blockIdx.x;
    int tid = threadIdx.x;
    double s = 0.0, s2 = 0.0;
    for (int b = 0; b < BB; ++b) {
        const float* p = feat + ((size_t)(b * CC + c)) * NN;
        for (int n = tid; n < NN; n += 1024) {
            double v = (double)p[n];
            s += v; s2 += v * v;
        }
    }
    __shared__ double sh[1024], sh2[1024];
    sh[tid] = s; sh2[tid] = s2;
    __syncthreads();
    for (int off = 512; off > 0; off >>= 1) {
        if (tid < off) { sh[tid] += sh[tid + off]; sh2[tid] += sh2[tid + off]; }
        __syncthreads();
    }
    if (tid == 0) {
        double inv = 1.0 / (double)(BB * NN);
        double mean = sh[0] * inv;
        double var = sh2[0] * inv - mean * mean;
        float sc = gamma[c] * (float)(1.0 / sqrt(var + (double)1e-5f));
        g_wsf[c] = sc;                                  // scale
        g_wsf[64 + c] = beta[c] - sc * (float)mean;     // shift
    }
}

// ---------------- kernel 2: feat0 = Wg' * [feat;xyz] + bias0 ----------------
__global__ __launch_bounds__(256) void k_feat0(const float* __restrict__ feat,
        const float* __restrict__ xyz, const float* __restrict__ Wg) {
    __shared__ float wgs[CP3 * FE];  // [c][e]
    __shared__ float bias0[FE];
    int tid = threadIdx.x;
    for (int i = tid; i < CP3 * FE; i += 256) {
        int c = i >> 5, e = i & 31;
        float w = Wg[e * CP3 + c];
        if (c < CC) w *= g_wsf[c];
        wgs[c * FE + e] = w;
    }
    if (tid < FE) {
        float sacc = 0.f;
        for (int c = 0; c < CC; ++c) sacc = fmaf(Wg[tid * CP3 + c], g_wsf[64 + c], sacc);
        bias0[tid] = sacc;
    }
    __syncthreads();
    int b = blockIdx.x >> 5;
    int n = ((blockIdx.x & 31) << 8) + tid;
    const float* pz = xyz + ((size_t)(b * NN + n)) * 3;
    float x = pz[0], y = pz[1], z = pz[2];

    float acc[FE];
    #pragma unroll
    for (int e = 0; e < FE; ++e) acc[e] = bias0[e];
    const float* fp = feat + (size_t)b * CC * NN + n;
    for (int c = 0; c < CC; ++c) {
        float v = fp[(size_t)c * NN];
        const float4* w4 = (const float4*)(wgs + c * FE);
        #pragma unroll
        for (int e0 = 0; e0 < 8; ++e0) {
            float4 w = w4[e0];
            acc[e0 * 4 + 0] = fmaf(w.x, v, acc[e0 * 4 + 0]);
            acc[e0 * 4 + 1] = fmaf(w.y, v, acc[e0 * 4 + 1]);
            acc[e0 * 4 + 2] = fmaf(w.z, v, acc[e0 * 4 + 2]);
            acc[e0 * 4 + 3] = fmaf(w.w, v, acc[e0 * 4 + 3]);
        }
    }
    #pragma unroll
    for (int d = 0; d < 3; ++d) {
        float v = (d == 0) ? x : ((d == 1) ? y : z);
        const float4* w4 = (const float4*)(wgs + (CC + d) * FE);
        #pragma unroll
        for (int e0 = 0; e0 < 8; ++e0) {
            float4 w = w4[e0];
            acc[e0 * 4 + 0] = fmaf(w.x, v, acc[e0 * 4 + 0]);
            acc[e0 * 4 + 1] = fmaf(w.y, v, acc[e0 * 4 + 1]);
            acc[e0 * 4 + 2] = fmaf(w.z, v, acc[e0 * 4 + 2]);
            acc[e0 * 4 + 3] = fmaf(w.w, v, acc[e0 * 4 + 3]);
        }
    }
    float4* outp = (float4*)(g_feat0 + ((size_t)(b * NN + n)) * FE);
    #pragma unroll
    for (int e0 = 0; e0 < 8; ++e0)
        outp[e0] = make_float4(acc[e0 * 4 + 0], acc[e0 * 4 + 1], acc[e0 * 4 + 2], acc[e0 * 4 + 3]);
}

// ---------------- kernel 3: multi-query wave KNN, LDS-atomic stacks -------
// FROZEN reference arithmetic (verified R5, XLA-CPU FMA contraction):
//   xx   = fma(z,z, fma(y,y, x*x))
//   dot  = fma(zq,zm, fma(yq,ym, xq*xm))
//   dist = fadd( fma(-2, dot, xx_q), xx_m )
// 4 queries/wave, 16/block. Passers pushed to per-query LDS stacks via
// atomicAdd (writes guarded pos<CAPQ -> no overrun possible). Exactness:
// accept iff 16 <= tot <= CAPQ (then stack holds ALL passers => superset of
// true top-16). Retry x2 / x0.5 only -- the R7-proven termination logic;
// R8's per-lane CAP added a third condition that oscillated (grow/shrink
// returning to the identical t0) and overran shared buffers. Removed.
__global__ __launch_bounds__(256) void k_knn(const float* __restrict__ xyz) {
    __shared__ float4 tilebuf[TILE];            // 8 KB
    __shared__ unsigned qbuf[QPB * CAPQ];       // 16 KB (indices only)
    __shared__ unsigned qcnt[QPB];
    int tid = threadIdx.x;
    int lane = tid & 63;
    int w = tid >> 6;
    int b = blockIdx.x >> 9;                    // 512 blocks per batch
    int n0 = (blockIdx.x & 511) * QPB;
    const float* bxyz = xyz + (size_t)b * NN * 3;

    float qx[QPW], qy[QPW], qz[QPW], qxx[QPW], t0[QPW];
    bool qdone[QPW];
    #pragma unroll
    for (int i = 0; i < QPW; ++i) {
        int qq = w * QPW + i;
        const float* pq = bxyz + (size_t)(n0 + qq) * 3;
        qx[i] = pq[0]; qy[i] = pq[1]; qz[i] = pq[2];
        qxx[i] = __fmaf_rn(qz[i], qz[i], __fmaf_rn(qy[i], qy[i], __fmul_rn(qx[i], qx[i])));
        float tt = 0.06f * __expf(qxx[i] * (1.0f / 3.0f));   // ~36 expected passers
        t0[i] = tt > 3.f ? 3.f : tt;
        qdone[i] = false;
    }
    if (tid < QPB) qcnt[tid] = 0;

    for (int attempt = 0; attempt < 40; ++attempt) {
        bool wact = !(qdone[0] && qdone[1] && qdone[2] && qdone[3]);
        for (int t = 0; t < NTILE; ++t) {
            __syncthreads();
            {   // stage 2 candidates per thread: float4{x,y,z,xx}
                int c0 = t * TILE + tid * 2;
                const float* p0 = bxyz + (size_t)c0 * 3;
                float ax = p0[0], ay = p0[1], az = p0[2];
                float bx = p0[3], by = p0[4], bz = p0[5];
                float axx = __fmaf_rn(az, az, __fmaf_rn(ay, ay, __fmul_rn(ax, ax)));
                float bxx = __fmaf_rn(bz, bz, __fmaf_rn(by, by, __fmul_rn(bx, bx)));
                tilebuf[tid * 2]     = make_float4(ax, ay, az, axx);
                tilebuf[tid * 2 + 1] = make_float4(bx, by, bz, bxx);
            }
            __syncthreads();
            if (!wact) continue;
            #pragma unroll
            for (int s = 0; s < TILE / 64; ++s) {
                float4 cc = tilebuf[s * 64 + lane];
                unsigned cand = (unsigned)(t * TILE + s * 64 + lane);
                #pragma unroll
                for (int i = 0; i < QPW; ++i) {
                    float dot = __fmaf_rn(qz[i], cc.z, __fmaf_rn(qy[i], cc.y, __fmul_rn(qx[i], cc.x)));
                    float dist = __fadd_rn(__fmaf_rn(-2.f, dot, qxx[i]), cc.w);
                    if (dist <= t0[i]) {
                        unsigned qq = (unsigned)(w * QPW + i);
                        unsigned pos = atomicAdd(&qcnt[qq], 1u);
                        if (pos < CAPQ) qbuf[qq * CAPQ + pos] = cand;
                    }
                }
            }
        }
        int again = 0;
        if (wact) {
            #pragma unroll
            for (int i = 0; i < QPW; ++i) {
                if (qdone[i]) continue;                  // wave-uniform
                unsigned qq = (unsigned)(w * QPW + i);
                unsigned tot = qcnt[qq];
                if (tot < KN)         { t0[i] *= 2.0f; if (lane == 0) qcnt[qq] = 0; again = 1; }
                else if (tot > CAPQ)  { t0[i] *= 0.5f; if (lane == 0) qcnt[qq] = 0; again = 1; }
                else { qdone[i] = true; t0[i] = -1.0e30f; }   // freeze stack
            }
        }
        if (!__syncthreads_or(again)) break;
    }

    // ---- selection: recompute frozen dist for survivors, u64 wave-min ----
    for (int i = 0; i < QPW; ++i) {
        unsigned qq = (unsigned)(w * QPW + i);
        unsigned tot = qcnt[qq];
        if (tot > CAPQ) tot = CAPQ;                      // unreachable safety
        const unsigned* pb = qbuf + qq * CAPQ;
        unsigned long long r[4];
        #pragma unroll
        for (int u = 0; u < 4; ++u) {
            unsigned j = (unsigned)(u * 64 + lane);
            r[u] = ~0ull;
            if (j < tot) {
                unsigned cand = pb[j];
                const float* pc = bxyz + (size_t)cand * 3;
                float cx = pc[0], cy = pc[1], cz = pc[2];
                float cxx = __fmaf_rn(cz, cz, __fmaf_rn(cy, cy, __fmul_rn(cx, cx)));
                float dot = __fmaf_rn(qz[i], cz, __fmaf_rn(qy[i], cy, __fmul_rn(qx[i], cx)));
                float dist = __fadd_rn(__fmaf_rn(-2.f, dot, qxx[i]), cxx);
                int bb2 = __float_as_int(dist);
                unsigned key = (unsigned)bb2 ^ (unsigned)((bb2 >> 31) | 0x80000000);
                r[u] = ((unsigned long long)key << 32) | cand;
            }
        }
        int obase = (b * NN + n0 + (int)qq) * KN;
        for (int k = 0; k < KN; ++k) {
            unsigned long long m01 = r[0] < r[1] ? r[0] : r[1];
            unsigned long long m23 = r[2] < r[3] ? r[2] : r[3];
            unsigned long long m = m01 < m23 ? m01 : m23;
            #pragma unroll
            for (int off = 32; off >= 1; off >>= 1) {
                unsigned long long o = __shfl_xor(m, off, 64);
                if (o < m) m = o;
            }
            if (lane == 0) g_idx[obase + k] = (int)(m & 0xffffffffull);
            r[0] = (r[0] == m) ? ~0ull : r[0];
            r[1] = (r[1] == m) ? ~0ull : r[1];
            r[2] = (r[2] == m) ? ~0ull : r[2];
            r[3] = (r[3] == m) ? ~0ull : r[3];
        }
    }
}

// ---------------- kernel 4: gather+max, rel, out = Wh' * rel ----------------
__global__ __launch_bounds__(256) void k_out(const float* __restrict__ Wh,
        float* __restrict__ out) {
    __shared__ float whs[CC * FE];
    int tid = threadIdx.x;
    for (int i = tid; i < CC * FE; i += 256) {
        int c = i >> 5, e = i & 31;
        float s = 0.f;
        #pragma unroll
        for (int m = 0; m < 4; ++m) s += Wh[c * 128 + m * 32 + e];
        whs[i] = s;
    }
    __syncthreads();
    int b = blockIdx.x >> 5;
    int n = ((blockIdx.x & 31) << 8) + tid;
    const int* ip = g_idx + (size_t)(b * NN + n) * KN;
    const float4* f0 = (const float4*)(g_feat0 + (size_t)b * NN * FE);
    float gmax[FE];
    #pragma unroll
    for (int e = 0; e < FE; ++e) gmax[e] = -__builtin_inff();
    for (int k = 0; k < KN; ++k) {
        int id = ip[k] & (NN - 1);      // defensive mask, no-op for valid idx
        const float4* row = f0 + (size_t)id * 8;
        #pragma unroll
        for (int e0 = 0; e0 < 8; ++e0) {
            float4 v = row[e0];
            gmax[e0 * 4 + 0] = fmaxf(gmax[e0 * 4 + 0], v.x);
            gmax[e0 * 4 + 1] = fmaxf(gmax[e0 * 4 + 1], v.y);
            gmax[e0 * 4 + 2] = fmaxf(gmax[e0 * 4 + 2], v.z);
            gmax[e0 * 4 + 3] = fmaxf(gmax[e0 * 4 + 3], v.w);
        }
    }
    const float4* selfr = f0 + (size_t)n * 8;
    float rel[FE];
    #pragma unroll
    for (int e0 = 0; e0 < 8; ++e0) {
        float4 v = selfr[e0];
        rel[e0 * 4 + 0] = gmax[e0 * 4 + 0] - v.x;
        rel[e0 * 4 + 1] = gmax[e0 * 4 + 1] - v.y;
        rel[e0 * 4 + 2] = gmax[e0 * 4 + 2] - v.z;
        rel[e0 * 4 + 3] = gmax[e0 * 4 + 3] - v.w;
    }
    float* op = out + (size_t)b * CC * NN + n;
    for (int c = 0; c < CC; ++c) {
        const float4* w4 = (const float4*)(whs + c * FE);
        float s = 0.f;
        #pragma unroll
        for (int e0 = 0; e0 < 8; ++e0) {
            float4 w = w4[e0];
            s = fmaf(w.x, rel[e0 * 4 + 0], s);
            s = fmaf(w.y, rel[e0 * 4 + 1], s);
            s = fmaf(w.z, rel[e0 * 4 + 2], s);
            s = fmaf(w.w, rel[e0 * 4 + 3], s);
        }
        op[(size_t)c * NN] = s;
    }
}

extern "C" void kernel_launch(void* const* d_in, const int* in_sizes, int n_in,
                              void* d_out, int out_size, void* d_ws, size_t ws_size,
                              hipStream_t stream) {
    const float* xyz   = (const float*)d_in[0];
    const float* feat  = (const float*)d_in[1];
    const float* gamma = (const float*)d_in[2];
    const float* beta  = (const float*)d_in[3];
    const float* Wg    = (const float*)d_in[4];
    const float* Wh    = (const float*)d_in[5];
    float* out = (float*)d_out;
    (void)d_ws; (void)ws_size;

    hipLaunchKernelGGL(k_bnstats, dim3(64),   dim3(1024), 0, stream, feat, gamma, beta);
    hipLaunchKernelGGL(k_feat0,   dim3(256),  dim3(256),  0, stream, feat, xyz, Wg);
    hipLaunchKernelGGL(k_knn,     dim3(4096), dim3(256),  0, stream, xyz);
    hipLaunchKernelGGL(k_out,     dim3(256),  dim3(256),  0, stream, Wh, out);
}

// Round 10
// 369.943 us; speedup vs baseline: 4.6719x; 1.0184x over previous
//
#include <hip/hip_runtime.h>
#include <math.h>

#define BB 8
#define NN 8192
#define CC 64
#define FE 32
#define KN 16
#define CP3 67
#define TILE 512
#define QPW 4                 // queries per wave
#define QPB 16                // queries per block (4 waves)
#define CAPQ 256              // per-query candidate stack (count-checked => exact)
#define ZBINS 64

// Device-global scratch (module .bss). All bytes written every launch before read.
__device__ float g_wsf[128];                  // scale[64], shift[64]
__device__ float g_feat0[BB * NN * FE];       // 8 MB
__device__ int   g_idx[BB * NN * KN];         // 4 MB
__device__ float4 g_sorted[BB * NN];          // z-bin-sorted {x,y,z,xx}
__device__ int    g_sorig[BB * NN];           // sorted -> original index
__device__ unsigned g_binoff[BB * (ZBINS + 1)];

// Identical in k_zbin and k_knn (same source => same bits; monotone in z).
__device__ __forceinline__ int zbin(float z) {
    int bi = (int)((z + 6.0f) * (16.0f / 3.0f));
    if (bi < 0) bi = 0;
    if (bi > ZBINS - 1) bi = ZBINS - 1;
    return bi;
}
// FROZEN reference xx (verified R5, XLA-CPU FMA contraction)
__device__ __forceinline__ float frz_xx(float x, float y, float z) {
    return __fmaf_rn(z, z, __fmaf_rn(y, y, __fmul_rn(x, x)));
}

// ---------------- kernel 1: BN stats -> scale/shift ----------------
__global__ __launch_bounds__(1024) void k_bnstats(const float* __restrict__ feat,
        const float* __restrict__ gamma, const float* __restrict__ beta) {
    int c = blockIdx.x;
    int tid = threadIdx.x;
    double s = 0.0, s2 = 0.0;
    for (int b = 0; b < BB; ++b) {
        const float* p = feat + ((size_t)(b * CC + c)) * NN;
        for (int n = tid; n < NN; n += 1024) {
            double v = (double)p[n];
            s += v; s2 += v * v;
        }
    }
    __shared__ double sh[1024], sh2[1024];
    sh[tid] = s; sh2[tid] = s2;
    __syncthreads();
    for (int off = 512; off > 0; off >>= 1) {
        if (tid < off) { sh[tid] += sh[tid + off]; sh2[tid] += sh2[tid + off]; }
        __syncthreads();
    }
    if (tid == 0) {
        double inv = 1.0 / (double)(BB * NN);
        double mean = sh[0] * inv;
        double var = sh2[0] * inv - mean * mean;
        float sc = gamma[c] * (float)(1.0 / sqrt(var + (double)1e-5f));
        g_wsf[c] = sc;
        g_wsf[64 + c] = beta[c] - sc * (float)mean;
    }
}

// ---------------- kernel 1b: z-binning (histogram + scatter) --------------
__global__ __launch_bounds__(1024) void k_zbin(const float* __restrict__ xyz) {
    __shared__ unsigned hist[ZBINS];
    __shared__ unsigned boff[ZBINS + 1];
    int b = blockIdx.x;
    int tid = threadIdx.x;
    if (tid < ZBINS) hist[tid] = 0;
    __syncthreads();
    const float* bx = xyz + (size_t)b * NN * 3;
    for (int n = tid; n < NN; n += 1024)
        atomicAdd(&hist[zbin(bx[n * 3 + 2])], 1u);
    __syncthreads();
    if (tid == 0) {
        unsigned s = 0;
        for (int i = 0; i < ZBINS; ++i) { boff[i] = s; s += hist[i]; }
        boff[ZBINS] = s;
    }
    __syncthreads();
    if (tid < ZBINS) hist[tid] = 0;            // reuse as cursors
    if (tid < ZBINS + 1) g_binoff[b * (ZBINS + 1) + tid] = boff[tid];
    __syncthreads();
    for (int n = tid; n < NN; n += 1024) {
        const float* p = bx + (size_t)n * 3;
        float x = p[0], y = p[1], z = p[2];
        unsigned pos = boff[zbin(z)] + atomicAdd(&hist[zbin(z)], 1u);
        g_sorted[(size_t)b * NN + pos] = make_float4(x, y, z, frz_xx(x, y, z));
        g_sorig[(size_t)b * NN + pos] = n;
    }
}

// ---------------- kernel 2: feat0 = Wg' * [feat;xyz] + bias0 ----------------
__global__ __launch_bounds__(256) void k_feat0(const float* __restrict__ feat,
        const float* __restrict__ xyz, const float* __restrict__ Wg) {
    __shared__ float wgs[CP3 * FE];
    __shared__ float bias0[FE];
    int tid = threadIdx.x;
    for (int i = tid; i < CP3 * FE; i += 256) {
        int c = i >> 5, e = i & 31;
        float w = Wg[e * CP3 + c];
        if (c < CC) w *= g_wsf[c];
        wgs[c * FE + e] = w;
    }
    if (tid < FE) {
        float sacc = 0.f;
        for (int c = 0; c < CC; ++c) sacc = fmaf(Wg[tid * CP3 + c], g_wsf[64 + c], sacc);
        bias0[tid] = sacc;
    }
    __syncthreads();
    int b = blockIdx.x >> 5;
    int n = ((blockIdx.x & 31) << 8) + tid;
    const float* pz = xyz + ((size_t)(b * NN + n)) * 3;
    float x = pz[0], y = pz[1], z = pz[2];

    float acc[FE];
    #pragma unroll
    for (int e = 0; e < FE; ++e) acc[e] = bias0[e];
    const float* fp = feat + (size_t)b * CC * NN + n;
    for (int c = 0; c < CC; ++c) {
        float v = fp[(size_t)c * NN];
        const float4* w4 = (const float4*)(wgs + c * FE);
        #pragma unroll
        for (int e0 = 0; e0 < 8; ++e0) {
            float4 w = w4[e0];
            acc[e0 * 4 + 0] = fmaf(w.x, v, acc[e0 * 4 + 0]);
            acc[e0 * 4 + 1] = fmaf(w.y, v, acc[e0 * 4 + 1]);
            acc[e0 * 4 + 2] = fmaf(w.z, v, acc[e0 * 4 + 2]);
            acc[e0 * 4 + 3] = fmaf(w.w, v, acc[e0 * 4 + 3]);
        }
    }
    #pragma unroll
    for (int d = 0; d < 3; ++d) {
        float v = (d == 0) ? x : ((d == 1) ? y : z);
        const float4* w4 = (const float4*)(wgs + (CC + d) * FE);
        #pragma unroll
        for (int e0 = 0; e0 < 8; ++e0) {
            float4 w = w4[e0];
            acc[e0 * 4 + 0] = fmaf(w.x, v, acc[e0 * 4 + 0]);
            acc[e0 * 4 + 1] = fmaf(w.y, v, acc[e0 * 4 + 1]);
            acc[e0 * 4 + 2] = fmaf(w.z, v, acc[e0 * 4 + 2]);
            acc[e0 * 4 + 3] = fmaf(w.w, v, acc[e0 * 4 + 3]);
        }
    }
    float4* outp = (float4*)(g_feat0 + ((size_t)(b * NN + n)) * FE);
    #pragma unroll
    for (int e0 = 0; e0 < 8; ++e0)
        outp[e0] = make_float4(acc[e0 * 4 + 0], acc[e0 * 4 + 1], acc[e0 * 4 + 2], acc[e0 * 4 + 3]);
}

// ---------------- kernel 3: z-windowed multi-query wave KNN ---------------
// FROZEN reference arithmetic (verified R5):
//   dot  = fma(zq,zm, fma(yq,ym, xq*xm))
//   dist = fadd( fma(-2, dot, xx_q), xx_m )
// Queries processed in z-sorted order; block of 16 z-adjacent queries scans
// only the sorted window covering [zq-R, zq+R] (R = sqrt(t0+1e-3)+1e-3, +-1
// bin): any frozen-dist passer has (cz-zq)^2 <= dist+1e-4 => inside window.
// Stacks/count-check/retry/selection identical to the R9-proven machinery.
__global__ __launch_bounds__(256) void k_knn(const float* __restrict__ xyz) {
    __shared__ float4 tilebuf[TILE];            // 8 KB
    __shared__ int    origbuf[TILE];            // 2 KB
    __shared__ unsigned qbuf[QPB * CAPQ];       // 16 KB
    __shared__ unsigned qcnt[QPB];
    __shared__ int swlo, swhi;
    int tid = threadIdx.x;
    int lane = tid & 63;
    int w = tid >> 6;
    int b = blockIdx.x >> 9;                    // 512 blocks per batch
    int n0 = (blockIdx.x & 511) * QPB;
    const float4* S = g_sorted + (size_t)b * NN;
    const int* SO = g_sorig + (size_t)b * NN;
    const unsigned* BO = g_binoff + b * (ZBINS + 1);
    const float* bxyz = xyz + (size_t)b * NN * 3;

    float qx[QPW], qy[QPW], qz[QPW], qxx[QPW], t0[QPW];
    int qorig[QPW];
    bool qdone[QPW];
    #pragma unroll
    for (int i = 0; i < QPW; ++i) {
        int qq = w * QPW + i;
        float4 qv = S[n0 + qq];
        qx[i] = qv.x; qy[i] = qv.y; qz[i] = qv.z; qxx[i] = qv.w;
        qorig[i] = SO[n0 + qq];
        float tt = 0.06f * __expf(qxx[i] * (1.0f / 3.0f));   // ~36 expected passers
        t0[i] = tt > 3.f ? 3.f : tt;
        qdone[i] = false;
    }
    if (tid < QPB) qcnt[tid] = 0;

    for (int attempt = 0; attempt < 40; ++attempt) {
        // ---- active-window reduce (bins) ----
        __syncthreads();
        if (tid == 0) { swlo = ZBINS; swhi = -1; }
        __syncthreads();
        if (lane == 0) {
            #pragma unroll
            for (int i = 0; i < QPW; ++i) {
                if (qdone[i]) continue;
                float R = __fsqrt_rn(t0[i] + 1e-3f) + 1e-3f;
                int blo = zbin(qz[i] - R) - 1; if (blo < 0) blo = 0;
                int bhi = zbin(qz[i] + R) + 1; if (bhi > ZBINS - 1) bhi = ZBINS - 1;
                atomicMin(&swlo, blo);
                atomicMax(&swhi, bhi);
            }
        }
        __syncthreads();
        int lo = (swhi < swlo) ? 0 : (int)BO[swlo];
        int hi = (swhi < swlo) ? 0 : (int)BO[swhi + 1];
        bool wact = !(qdone[0] && qdone[1] && qdone[2] && qdone[3]);

        for (int p = lo; p < hi; p += TILE) {
            __syncthreads();
            #pragma unroll
            for (int u = 0; u < 2; ++u) {
                int j = p + tid * 2 + u;
                // pad: coords 0, xx=+1e30 -> dist = xxq+1e30, can never pass
                float4 v = (j < hi) ? S[j] : make_float4(0.f, 0.f, 0.f, 1e30f);
                int o = (j < hi) ? SO[j] : 0;
                tilebuf[tid * 2 + u] = v;
                origbuf[tid * 2 + u] = o;
            }
            __syncthreads();
            if (!wact) continue;
            #pragma unroll
            for (int s = 0; s < TILE / 64; ++s) {
                float4 cc = tilebuf[s * 64 + lane];
                int corig = origbuf[s * 64 + lane];
                #pragma unroll
                for (int i = 0; i < QPW; ++i) {
                    float dot = __fmaf_rn(qz[i], cc.z, __fmaf_rn(qy[i], cc.y, __fmul_rn(qx[i], cc.x)));
                    float dist = __fadd_rn(__fmaf_rn(-2.f, dot, qxx[i]), cc.w);
                    if (dist <= t0[i]) {
                        unsigned qq = (unsigned)(w * QPW + i);
                        unsigned pos = atomicAdd(&qcnt[qq], 1u);
                        if (pos < CAPQ) qbuf[qq * CAPQ + pos] = (unsigned)corig;
                    }
                }
            }
        }
        int again = 0;
        if (wact) {
            #pragma unroll
            for (int i = 0; i < QPW; ++i) {
                if (qdone[i]) continue;                  // wave-uniform
                unsigned qq = (unsigned)(w * QPW + i);
                unsigned tot = qcnt[qq];
                if (tot < KN)         { t0[i] *= 2.0f; if (lane == 0) qcnt[qq] = 0; again = 1; }
                else if (tot > CAPQ)  { t0[i] *= 0.5f; if (lane == 0) qcnt[qq] = 0; again = 1; }
                else { qdone[i] = true; t0[i] = -1.0e30f; }   // freeze stack
            }
        }
        if (!__syncthreads_or(again)) break;
    }

    // ---- selection: recompute frozen dist for survivors, u64 wave-min ----
    for (int i = 0; i < QPW; ++i) {
        unsigned qq = (unsigned)(w * QPW + i);
        unsigned tot = qcnt[qq];
        if (tot > CAPQ) tot = CAPQ;                      // unreachable safety
        const unsigned* pb = qbuf + qq * CAPQ;
        unsigned long long r[4];
        #pragma unroll
        for (int u = 0; u < 4; ++u) {
            unsigned j = (unsigned)(u * 64 + lane);
            r[u] = ~0ull;
            if (j < tot) {
                unsigned cand = pb[j];
                const float* pc = bxyz + (size_t)cand * 3;
                float cx = pc[0], cy = pc[1], cz = pc[2];
                float cxx = frz_xx(cx, cy, cz);
                float dot = __fmaf_rn(qz[i], cz, __fmaf_rn(qy[i], cy, __fmul_rn(qx[i], cx)));
                float dist = __fadd_rn(__fmaf_rn(-2.f, dot, qxx[i]), cxx);
                int bb2 = __float_as_int(dist);
                unsigned key = (unsigned)bb2 ^ (unsigned)((bb2 >> 31) | 0x80000000);
                r[u] = ((unsigned long long)key << 32) | cand;
            }
        }
        int obase = (b * NN + qorig[i]) * KN;
        for (int k = 0; k < KN; ++k) {
            unsigned long long m01 = r[0] < r[1] ? r[0] : r[1];
            unsigned long long m23 = r[2] < r[3] ? r[2] : r[3];
            unsigned long long m = m01 < m23 ? m01 : m23;
            #pragma unroll
            for (int off = 32; off >= 1; off >>= 1) {
                unsigned long long o = __shfl_xor(m, off, 64);
                if (o < m) m = o;
            }
            if (lane == 0) g_idx[obase + k] = (int)(m & 0xffffffffull);
            r[0] = (r[0] == m) ? ~0ull : r[0];
            r[1] = (r[1] == m) ? ~0ull : r[1];
            r[2] = (r[2] == m) ? ~0ull : r[2];
            r[3] = (r[3] == m) ? ~0ull : r[3];
        }
    }
}

// ---------------- kernel 4: gather+max, rel, out = Wh' * rel ----------------
__global__ __launch_bounds__(256) void k_out(const float* __restrict__ Wh,
        float* __restrict__ out) {
    __shared__ float whs[CC * FE];
    int tid = threadIdx.x;
    for (int i = tid; i < CC * FE; i += 256) {
        int c = i >> 5, e = i & 31;
        float s = 0.f;
        #pragma unroll
        for (int m = 0; m < 4; ++m) s += Wh[c * 128 + m * 32 + e];
        whs[i] = s;
    }
    __syncthreads();
    int b = blockIdx.x >> 5;
    int n = ((blockIdx.x & 31) << 8) + tid;
    const int* ip = g_idx + (size_t)(b * NN + n) * KN;
    const float4* f0 = (const float4*)(g_feat0 + (size_t)b * NN * FE);
    float gmax[FE];
    #pragma unroll
    for (int e = 0; e < FE; ++e) gmax[e] = -__builtin_inff();
    for (int k = 0; k < KN; ++k) {
        int id = ip[k] & (NN - 1);      // defensive mask, no-op for valid idx
        const float4* row = f0 + (size_t)id * 8;
        #pragma unroll
        for (int e0 = 0; e0 < 8; ++e0) {
            float4 v = row[e0];
            gmax[e0 * 4 + 0] = fmaxf(gmax[e0 * 4 + 0], v.x);
            gmax[e0 * 4 + 1] = fmaxf(gmax[e0 * 4 + 1], v.y);
            gmax[e0 * 4 + 2] = fmaxf(gmax[e0 * 4 + 2], v.z);
            gmax[e0 * 4 + 3] = fmaxf(gmax[e0 * 4 + 3], v.w);
        }
    }
    const float4* selfr = f0 + (size_t)n * 8;
    float rel[FE];
    #pragma unroll
    for (int e0 = 0; e0 < 8; ++e0) {
        float4 v = selfr[e0];
        rel[e0 * 4 + 0] = gmax[e0 * 4 + 0] - v.x;
        rel[e0 * 4 + 1] = gmax[e0 * 4 + 1] - v.y;
        rel[e0 * 4 + 2] = gmax[e0 * 4 + 2] - v.z;
        rel[e0 * 4 + 3] = gmax[e0 * 4 + 3] - v.w;
    }
    float* op = out + (size_t)b * CC * NN + n;
    for (int c = 0; c < CC; ++c) {
        const float4* w4 = (const float4*)(whs + c * FE);
        float s = 0.f;
        #pragma unroll
        for (int e0 = 0; e0 < 8; ++e0) {
            float4 w = w4[e0];
            s = fmaf(w.x, rel[e0 * 4 + 0], s);
            s = fmaf(w.y, rel[e0 * 4 + 1], s);
            s = fmaf(w.z, rel[e0 * 4 + 2], s);
            s = fmaf(w.w, rel[e0 * 4 + 3], s);
        }
        op[(size_t)c * NN] = s;
    }
}

extern "C" void kernel_launch(void* const* d_in, const int* in_sizes, int n_in,
                              void* d_out, int out_size, void* d_ws, size_t ws_size,
                              hipStream_t stream) {
    const float* xyz   = (const float*)d_in[0];
    const float* feat  = (const float*)d_in[1];
    const float* gamma = (const float*)d_in[2];
    const float* beta  = (const float*)d_in[3];
    const float* Wg    = (const float*)d_in[4];
    const float* Wh    = (const float*)d_in[5];
    float* out = (float*)d_out;
    (void)d_ws; (void)ws_size;

    hipLaunchKernelGGL(k_bnstats, dim3(64),   dim3(1024), 0, stream, feat, gamma, beta);
    hipLaunchKernelGGL(k_zbin,    dim3(8),    dim3(1024), 0, stream, xyz);
    hipLaunchKernelGGL(k_feat0,   dim3(256),  dim3(256),  0, stream, feat, xyz, Wg);
    hipLaunchKernelGGL(k_knn,     dim3(4096), dim3(256),  0, stream, xyz);
    hipLaunchKernelGGL(k_out,     dim3(256),  dim3(256),  0, stream, Wh, out);
}

// Round 12
// 360.223 us; speedup vs baseline: 4.7980x; 1.0270x over previous
//
#include <hip/hip_runtime.h>
#include <math.h>

#define BB 8
#define NN 8192
#define CC 64
#define FE 32
#define KN 16
#define CP3 67
#define QPW 8                 // queries per wave (z-adjacent)
#define WPB 4                 // waves per block
#define CAPQ 128              // per-query stack (count-checked => exact)
#define ZBINS 64

// Device-global scratch (module .bss). All bytes written every launch before read.
__device__ float g_wsf[128];                  // scale[64], shift[64]
__device__ float g_feat0[BB * NN * FE];       // 8 MB
__device__ int   g_idx[BB * NN * KN];         // 4 MB
__device__ float4 g_sorted[BB * NN];          // z-bin-sorted {x,y,z,xx}
__device__ int    g_sorig[BB * NN];           // sorted -> original index
__device__ unsigned g_binoff[BB * (ZBINS + 1)];

// Identical in k_zbin and k_knn (same source => same bits; monotone in z).
__device__ __forceinline__ int zbin(float z) {
    int bi = (int)((z + 6.0f) * (16.0f / 3.0f));
    if (bi < 0) bi = 0;
    if (bi > ZBINS - 1) bi = ZBINS - 1;
    return bi;
}
// FROZEN reference xx (verified R5, XLA-CPU FMA contraction)
__device__ __forceinline__ float frz_xx(float x, float y, float z) {
    return __fmaf_rn(z, z, __fmaf_rn(y, y, __fmul_rn(x, x)));
}

// ---------------- kernel 1: BN stats -> scale/shift ----------------
__global__ __launch_bounds__(1024) void k_bnstats(const float* __restrict__ feat,
        const float* __restrict__ gamma, const float* __restrict__ beta) {
    int c = blockIdx.x;
    int tid = threadIdx.x;
    double s = 0.0, s2 = 0.0;
    for (int b = 0; b < BB; ++b) {
        const float* p = feat + ((size_t)(b * CC + c)) * NN;
        for (int n = tid; n < NN; n += 1024) {
            double v = (double)p[n];
            s += v; s2 += v * v;
        }
    }
    __shared__ double sh[1024], sh2[1024];
    sh[tid] = s; sh2[tid] = s2;
    __syncthreads();
    for (int off = 512; off > 0; off >>= 1) {
        if (tid < off) { sh[tid] += sh[tid + off]; sh2[tid] += sh2[tid + off]; }
        __syncthreads();
    }
    if (tid == 0) {
        double inv = 1.0 / (double)(BB * NN);
        double mean = sh[0] * inv;
        double var = sh2[0] * inv - mean * mean;
        float sc = gamma[c] * (float)(1.0 / sqrt(var + (double)1e-5f));
        g_wsf[c] = sc;
        g_wsf[64 + c] = beta[c] - sc * (float)mean;
    }
}

// ---------------- kernel 1b: z-binning (histogram + scatter) --------------
__global__ __launch_bounds__(1024) void k_zbin(const float* __restrict__ xyz) {
    __shared__ unsigned hist[ZBINS];
    __shared__ unsigned boff[ZBINS + 1];
    int b = blockIdx.x;
    int tid = threadIdx.x;
    if (tid < ZBINS) hist[tid] = 0;
    __syncthreads();
    const float* bx = xyz + (size_t)b * NN * 3;
    for (int n = tid; n < NN; n += 1024)
        atomicAdd(&hist[zbin(bx[n * 3 + 2])], 1u);
    __syncthreads();
    if (tid == 0) {
        unsigned s = 0;
        for (int i = 0; i < ZBINS; ++i) { boff[i] = s; s += hist[i]; }
        boff[ZBINS] = s;
    }
    __syncthreads();
    if (tid < ZBINS) hist[tid] = 0;            // reuse as cursors
    if (tid < ZBINS + 1) g_binoff[b * (ZBINS + 1) + tid] = boff[tid];
    __syncthreads();
    for (int n = tid; n < NN; n += 1024) {
        const float* p = bx + (size_t)n * 3;
        float x = p[0], y = p[1], z = p[2];
        unsigned pos = boff[zbin(z)] + atomicAdd(&hist[zbin(z)], 1u);
        g_sorted[(size_t)b * NN + pos] = make_float4(x, y, z, frz_xx(x, y, z));
        g_sorig[(size_t)b * NN + pos] = n;
    }
}

// ---------------- kernel 2: feat0 = Wg' * [feat;xyz] + bias0 ----------------
__global__ __launch_bounds__(256) void k_feat0(const float* __restrict__ feat,
        const float* __restrict__ xyz, const float* __restrict__ Wg) {
    __shared__ float wgs[CP3 * FE];
    __shared__ float bias0[FE];
    int tid = threadIdx.x;
    for (int i = tid; i < CP3 * FE; i += 256) {
        int c = i >> 5, e = i & 31;
        float w = Wg[e * CP3 + c];
        if (c < CC) w *= g_wsf[c];
        wgs[c * FE + e] = w;
    }
    if (tid < FE) {
        float sacc = 0.f;
        for (int c = 0; c < CC; ++c) sacc = fmaf(Wg[tid * CP3 + c], g_wsf[64 + c], sacc);
        bias0[tid] = sacc;
    }
    __syncthreads();
    int b = blockIdx.x >> 5;
    int n = ((blockIdx.x & 31) << 8) + tid;
    const float* pz = xyz + ((size_t)(b * NN + n)) * 3;
    float x = pz[0], y = pz[1], z = pz[2];

    float acc[FE];
    #pragma unroll
    for (int e = 0; e < FE; ++e) acc[e] = bias0[e];
    const float* fp = feat + (size_t)b * CC * NN + n;
    for (int c = 0; c < CC; ++c) {
        float v = fp[(size_t)c * NN];
        const float4* w4 = (const float4*)(wgs + c * FE);
        #pragma unroll
        for (int e0 = 0; e0 < 8; ++e0) {
            float4 w = w4[e0];
            acc[e0 * 4 + 0] = fmaf(w.x, v, acc[e0 * 4 + 0]);
            acc[e0 * 4 + 1] = fmaf(w.y, v, acc[e0 * 4 + 1]);
            acc[e0 * 4 + 2] = fmaf(w.z, v, acc[e0 * 4 + 2]);
            acc[e0 * 4 + 3] = fmaf(w.w, v, acc[e0 * 4 + 3]);
        }
    }
    #pragma unroll
    for (int d = 0; d < 3; ++d) {
        float v = (d == 0) ? x : ((d == 1) ? y : z);
        const float4* w4 = (const float4*)(wgs + (CC + d) * FE);
        #pragma unroll
        for (int e0 = 0; e0 < 8; ++e0) {
            float4 w = w4[e0];
            acc[e0 * 4 + 0] = fmaf(w.x, v, acc[e0 * 4 + 0]);
            acc[e0 * 4 + 1] = fmaf(w.y, v, acc[e0 * 4 + 1]);
            acc[e0 * 4 + 2] = fmaf(w.z, v, acc[e0 * 4 + 2]);
            acc[e0 * 4 + 3] = fmaf(w.w, v, acc[e0 * 4 + 3]);
        }
    }
    float4* outp = (float4*)(g_feat0 + ((size_t)(b * NN + n)) * FE);
    #pragma unroll
    for (int e0 = 0; e0 < 8; ++e0)
        outp[e0] = make_float4(acc[e0 * 4 + 0], acc[e0 * 4 + 1], acc[e0 * 4 + 2], acc[e0 * 4 + 3]);
}

// ---------------- kernel 3: autonomous-wave z-windowed KNN ---------------
// FROZEN reference arithmetic (verified R5):
//   dot  = fma(zq,zm, fma(yq,ym, xq*xm))
//   dist = fadd( fma(-2, dot, xx_q), xx_m )
// One wave owns 8 z-adjacent queries; no __syncthreads, no LDS atomics.
// Exactness: accept iff 16 <= cnt <= CAPQ (stack then holds ALL gate
// passers; z-window [zq-R,zq+R], R=sqrt(t0+1e-3)+1e-3 (+-1 bin) covers the
// gate set). Threshold search: BRACKETED GEOMETRIC BISECTION --
//   cnt<16  -> tlo=t0;  cnt>CAPQ -> thi=t0;  next t0 = sqrt(tlo*thi)
//   (x2 / x0.5 while unbracketed). Accepting set [d16,d17) is nonempty and
// cnt is monotone in t0 => provably converges (~<=12 attempts); kills the
// R11 oscillation (steep-count outliers jumped the narrowed window under
// blind x2/x0.5, exiting not-done -> garbage indices -> absmax 6.14).
__global__ __launch_bounds__(256) void k_knn() {
    __shared__ unsigned long long qbuf[WPB * QPW * CAPQ];   // 32 KB
    int tid = threadIdx.x;
    int lane = tid & 63;
    int w = tid >> 6;
    int wid = blockIdx.x * WPB + w;             // 0..8191
    int b = wid >> 10;                          // 1024 waves per batch
    int n0 = (wid & 1023) * QPW;
    const float4* S = g_sorted + (size_t)b * NN;
    const int* SO = g_sorig + (size_t)b * NN;
    const unsigned* BO = g_binoff + b * (ZBINS + 1);
    unsigned long long lt = (1ull << lane) - 1ull;

    float qx[QPW], qy[QPW], qz[QPW], qxx[QPW], t0[QPW], tlo[QPW], thi[QPW];
    int qorig[QPW];
    unsigned cnt[QPW];
    bool qdone[QPW];
    #pragma unroll
    for (int i = 0; i < QPW; ++i) {
        float4 qv = S[n0 + i];
        qx[i] = qv.x; qy[i] = qv.y; qz[i] = qv.z; qxx[i] = qv.w;
        qorig[i] = SO[n0 + i];
        float tt = 0.06f * __expf(qxx[i] * (1.0f / 3.0f));   // ~36 expected passers
        t0[i] = tt > 3.f ? 3.f : tt;
        tlo[i] = 0.f; thi[i] = 0.f;             // 0 = unset bracket ends
        cnt[i] = 0;
        qdone[i] = false;
    }

    for (int attempt = 0; attempt < 40; ++attempt) {
        // wave-private window over active queries (uniform arithmetic)
        float zlo = 1e30f, zhi = -1e30f;
        bool anyact = false;
        #pragma unroll
        for (int i = 0; i < QPW; ++i) {
            if (qdone[i]) continue;
            anyact = true;
            float R = __fsqrt_rn(t0[i] + 1e-3f) + 1e-3f;
            zlo = fminf(zlo, qz[i] - R);
            zhi = fmaxf(zhi, qz[i] + R);
        }
        if (!anyact) break;
        int blo = zbin(zlo) - 1; if (blo < 0) blo = 0;
        int bhi = zbin(zhi) + 1; if (bhi > ZBINS - 1) bhi = ZBINS - 1;
        int lo = (int)BO[blo];
        int hi = (int)BO[bhi + 1];

        for (int p = lo; p < hi; p += 64) {
            int jj = p + lane;
            int j = jj < hi ? jj : hi - 1;
            float4 cc = S[j];
            int corig = SO[j];
            unsigned long long inbm = __ballot(jj < hi);
            #pragma unroll
            for (int i = 0; i < QPW; ++i) {
                if (qdone[i]) continue;                       // uniform branch
                float dot = __fmaf_rn(qz[i], cc.z, __fmaf_rn(qy[i], cc.y, __fmul_rn(qx[i], cc.x)));
                float dist = __fadd_rn(__fmaf_rn(-2.f, dot, qxx[i]), cc.w);
                unsigned long long mask = __ballot(dist <= t0[i]) & inbm;
                if (mask) {
                    bool pr = (dist <= t0[i]) && (jj < hi);
                    unsigned pos = cnt[i] + (unsigned)__popcll(mask & lt);
                    if (pr && pos < CAPQ) {
                        int db = __float_as_int(dist);
                        unsigned key = (unsigned)db ^ (unsigned)((db >> 31) | 0x80000000);
                        qbuf[(w * QPW + i) * CAPQ + pos] =
                            ((unsigned long long)key << 32) | (unsigned)corig;
                    }
                    cnt[i] += (unsigned)__popcll(mask);
                }
            }
        }
        #pragma unroll
        for (int i = 0; i < QPW; ++i) {
            if (qdone[i]) continue;
            if (cnt[i] < KN) {
                tlo[i] = t0[i];
                t0[i] = (thi[i] > 0.f) ? __fsqrt_rn(tlo[i] * thi[i]) : t0[i] * 2.0f;
                cnt[i] = 0;
            } else if (cnt[i] > CAPQ) {
                thi[i] = t0[i];
                t0[i] = (tlo[i] > 0.f) ? __fsqrt_rn(tlo[i] * thi[i]) : t0[i] * 0.5f;
                cnt[i] = 0;
            } else {
                qdone[i] = true; t0[i] = -1.0e30f;           // freeze stack
            }
        }
    }

    // ---- selection: u64 extract-16 wave-min per query (keys pre-packed) ----
    #pragma unroll
    for (int i = 0; i < QPW; ++i) {
        unsigned tot = cnt[i] > CAPQ ? CAPQ : cnt[i];
        const unsigned long long* pb = qbuf + (w * QPW + i) * CAPQ;
        unsigned long long r0 = ((unsigned)lane < tot)        ? pb[lane]      : ~0ull;
        unsigned long long r1 = ((unsigned)(64 + lane) < tot) ? pb[64 + lane] : ~0ull;
        unsigned sel = 0xffffffffu;
        for (int k = 0; k < KN; ++k) {
            unsigned long long m = r0 < r1 ? r0 : r1;
            #pragma unroll
            for (int off = 32; off >= 1; off >>= 1) {
                unsigned long long o = __shfl_xor(m, off, 64);
                if (o < m) m = o;
            }
            if (lane == k) sel = (unsigned)(m & 0xffffffffull);
            r0 = (r0 == m) ? ~0ull : r0;
            r1 = (r1 == m) ? ~0ull : r1;
        }
        if (lane < KN)
            g_idx[(b * NN + qorig[i]) * KN + lane] = (int)sel;
    }
}

// ---------------- kernel 4: gather+max, rel, out = Wh' * rel ----------------
__global__ __launch_bounds__(256) void k_out(const float* __restrict__ Wh,
        float* __restrict__ out) {
    __shared__ float whs[CC * FE];
    int tid = threadIdx.x;
    for (int i = tid; i < CC * FE; i += 256) {
        int c = i >> 5, e = i & 31;
        float s = 0.f;
        #pragma unroll
        for (int m = 0; m < 4; ++m) s += Wh[c * 128 + m * 32 + e];
        whs[i] = s;
    }
    __syncthreads();
    int b = blockIdx.x >> 5;
    int n = ((blockIdx.x & 31) << 8) + tid;
    const int* ip = g_idx + (size_t)(b * NN + n) * KN;
    const float4* f0 = (const float4*)(g_feat0 + (size_t)b * NN * FE);
    float gmax[FE];
    #pragma unroll
    for (int e = 0; e < FE; ++e) gmax[e] = -__builtin_inff();
    for (int k = 0; k < KN; ++k) {
        int id = ip[k] & (NN - 1);      // defensive mask, no-op for valid idx
        const float4* row = f0 + (size_t)id * 8;
        #pragma unroll
        for (int e0 = 0; e0 < 8; ++e0) {
            float4 v = row[e0];
            gmax[e0 * 4 + 0] = fmaxf(gmax[e0 * 4 + 0], v.x);
            gmax[e0 * 4 + 1] = fmaxf(gmax[e0 * 4 + 1], v.y);
            gmax[e0 * 4 + 2] = fmaxf(gmax[e0 * 4 + 2], v.z);
            gmax[e0 * 4 + 3] = fmaxf(gmax[e0 * 4 + 3], v.w);
        }
    }
    const float4* selfr = f0 + (size_t)n * 8;
    float rel[FE];
    #pragma unroll
    for (int e0 = 0; e0 < 8; ++e0) {
        float4 v = selfr[e0];
        rel[e0 * 4 + 0] = gmax[e0 * 4 + 0] - v.x;
        rel[e0 * 4 + 1] = gmax[e0 * 4 + 1] - v.y;
        rel[e0 * 4 + 2] = gmax[e0 * 4 + 2] - v.z;
        rel[e0 * 4 + 3] = gmax[e0 * 4 + 3] - v.w;
    }
    float* op = out + (size_t)b * CC * NN + n;
    for (int c = 0; c < CC; ++c) {
        const float4* w4 = (const float4*)(whs + c * FE);
        float s = 0.f;
        #pragma unroll
        for (int e0 = 0; e0 < 8; ++e0) {
            float4 w = w4[e0];
            s = fmaf(w.x, rel[e0 * 4 + 0], s);
            s = fmaf(w.y, rel[e0 * 4 + 1], s);
            s = fmaf(w.z, rel[e0 * 4 + 2], s);
            s = fmaf(w.w, rel[e0 * 4 + 3], s);
        }
        op[(size_t)c * NN] = s;
    }
}

extern "C" void kernel_launch(void* const* d_in, const int* in_sizes, int n_in,
                              void* d_out, int out_size, void* d_ws, size_t ws_size,
                              hipStream_t stream) {
    const float* xyz   = (const float*)d_in[0];
    const float* feat  = (const float*)d_in[1];
    const float* gamma = (const float*)d_in[2];
    const float* beta  = (const float*)d_in[3];
    const float* Wg    = (const float*)d_in[4];
    const float* Wh    = (const float*)d_in[5];
    float* out = (float*)d_out;
    (void)d_ws; (void)ws_size;

    hipLaunchKernelGGL(k_bnstats, dim3(64),   dim3(1024), 0, stream, feat, gamma, beta);
    hipLaunchKernelGGL(k_zbin,    dim3(8),    dim3(1024), 0, stream, xyz);
    hipLaunchKernelGGL(k_feat0,   dim3(256),  dim3(256),  0, stream, feat, xyz, Wg);
    hipLaunchKernelGGL(k_knn,     dim3(2048), dim3(256),  0, stream);
    hipLaunchKernelGGL(k_out,     dim3(256),  dim3(256),  0, stream, Wh, out);
}

// Round 13
// 306.522 us; speedup vs baseline: 5.6386x; 1.1752x over previous
//
#include <hip/hip_runtime.h>
#include <math.h>

#define BB 8
#define NN 8192
#define CC 64
#define FE 32
#define KN 16
#define CP3 67
#define QPW 8                 // queries per wave (z-adjacent)
#define WPB 4                 // waves per block
#define CAPQ 64               // per-query stack (count-checked => exact)
#define ZBINS 256

// Device-global scratch (module .bss). All bytes written every launch before read.
__device__ float g_wsf[128];                  // scale[64], shift[64]
__device__ float g_feat0[BB * NN * FE];       // 8 MB
__device__ int   g_idx[BB * NN * KN];         // 4 MB
__device__ float4 g_sorted[BB * NN];          // z-bin-sorted {x,y,z,xx}
__device__ int    g_sorig[BB * NN];           // sorted -> original index
__device__ unsigned g_binoff[BB * (ZBINS + 1)];

// Identical in k_zbin and k_knn (same source => same bits; monotone in z).
__device__ __forceinline__ int zbin(float z) {
    int bi = (int)((z + 6.0f) * (64.0f / 3.0f));   // 256 bins over [-6,6]
    if (bi < 0) bi = 0;
    if (bi > ZBINS - 1) bi = ZBINS - 1;
    return bi;
}
// FROZEN reference xx (verified R5, XLA-CPU FMA contraction)
__device__ __forceinline__ float frz_xx(float x, float y, float z) {
    return __fmaf_rn(z, z, __fmaf_rn(y, y, __fmul_rn(x, x)));
}

// ---------------- kernel 1: BN stats -> scale/shift ----------------
__global__ __launch_bounds__(1024) void k_bnstats(const float* __restrict__ feat,
        const float* __restrict__ gamma, const float* __restrict__ beta) {
    int c = blockIdx.x;
    int tid = threadIdx.x;
    double s = 0.0, s2 = 0.0;
    for (int b = 0; b < BB; ++b) {
        const float* p = feat + ((size_t)(b * CC + c)) * NN;
        for (int n = tid; n < NN; n += 1024) {
            double v = (double)p[n];
            s += v; s2 += v * v;
        }
    }
    __shared__ double sh[1024], sh2[1024];
    sh[tid] = s; sh2[tid] = s2;
    __syncthreads();
    for (int off = 512; off > 0; off >>= 1) {
        if (tid < off) { sh[tid] += sh[tid + off]; sh2[tid] += sh2[tid + off]; }
        __syncthreads();
    }
    if (tid == 0) {
        double inv = 1.0 / (double)(BB * NN);
        double mean = sh[0] * inv;
        double var = sh2[0] * inv - mean * mean;
        float sc = gamma[c] * (float)(1.0 / sqrt(var + (double)1e-5f));
        g_wsf[c] = sc;
        g_wsf[64 + c] = beta[c] - sc * (float)mean;
    }
}

// ---------------- kernel 1b: z-binning (histogram + scatter) --------------
__global__ __launch_bounds__(1024) void k_zbin(const float* __restrict__ xyz) {
    __shared__ unsigned hist[ZBINS];
    __shared__ unsigned boff[ZBINS + 1];
    int b = blockIdx.x;
    int tid = threadIdx.x;
    if (tid < ZBINS) hist[tid] = 0;
    __syncthreads();
    const float* bx = xyz + (size_t)b * NN * 3;
    for (int n = tid; n < NN; n += 1024)
        atomicAdd(&hist[zbin(bx[n * 3 + 2])], 1u);
    __syncthreads();
    if (tid == 0) {
        unsigned s = 0;
        for (int i = 0; i < ZBINS; ++i) { boff[i] = s; s += hist[i]; }
        boff[ZBINS] = s;
    }
    __syncthreads();
    if (tid < ZBINS) hist[tid] = 0;            // reuse as cursors
    if (tid < ZBINS + 1) g_binoff[b * (ZBINS + 1) + tid] = boff[tid];
    __syncthreads();
    for (int n = tid; n < NN; n += 1024) {
        const float* p = bx + (size_t)n * 3;
        float x = p[0], y = p[1], z = p[2];
        unsigned pos = boff[zbin(z)] + atomicAdd(&hist[zbin(z)], 1u);
        g_sorted[(size_t)b * NN + pos] = make_float4(x, y, z, frz_xx(x, y, z));
        g_sorig[(size_t)b * NN + pos] = n;
    }
}

// ---------------- kernel 2: feat0 = Wg' * [feat;xyz] + bias0 ----------------
__global__ __launch_bounds__(256) void k_feat0(const float* __restrict__ feat,
        const float* __restrict__ xyz, const float* __restrict__ Wg) {
    __shared__ float wgs[CP3 * FE];
    __shared__ float bias0[FE];
    int tid = threadIdx.x;
    for (int i = tid; i < CP3 * FE; i += 256) {
        int c = i >> 5, e = i & 31;
        float w = Wg[e * CP3 + c];
        if (c < CC) w *= g_wsf[c];
        wgs[c * FE + e] = w;
    }
    if (tid < FE) {
        float sacc = 0.f;
        for (int c = 0; c < CC; ++c) sacc = fmaf(Wg[tid * CP3 + c], g_wsf[64 + c], sacc);
        bias0[tid] = sacc;
    }
    __syncthreads();
    int b = blockIdx.x >> 5;
    int n = ((blockIdx.x & 31) << 8) + tid;
    const float* pz = xyz + ((size_t)(b * NN + n)) * 3;
    float x = pz[0], y = pz[1], z = pz[2];

    float acc[FE];
    #pragma unroll
    for (int e = 0; e < FE; ++e) acc[e] = bias0[e];
    const float* fp = feat + (size_t)b * CC * NN + n;
    for (int c = 0; c < CC; ++c) {
        float v = fp[(size_t)c * NN];
        const float4* w4 = (const float4*)(wgs + c * FE);
        #pragma unroll
        for (int e0 = 0; e0 < 8; ++e0) {
            float4 w = w4[e0];
            acc[e0 * 4 + 0] = fmaf(w.x, v, acc[e0 * 4 + 0]);
            acc[e0 * 4 + 1] = fmaf(w.y, v, acc[e0 * 4 + 1]);
            acc[e0 * 4 + 2] = fmaf(w.z, v, acc[e0 * 4 + 2]);
            acc[e0 * 4 + 3] = fmaf(w.w, v, acc[e0 * 4 + 3]);
        }
    }
    #pragma unroll
    for (int d = 0; d < 3; ++d) {
        float v = (d == 0) ? x : ((d == 1) ? y : z);
        const float4* w4 = (const float4*)(wgs + (CC + d) * FE);
        #pragma unroll
        for (int e0 = 0; e0 < 8; ++e0) {
            float4 w = w4[e0];
            acc[e0 * 4 + 0] = fmaf(w.x, v, acc[e0 * 4 + 0]);
            acc[e0 * 4 + 1] = fmaf(w.y, v, acc[e0 * 4 + 1]);
            acc[e0 * 4 + 2] = fmaf(w.z, v, acc[e0 * 4 + 2]);
            acc[e0 * 4 + 3] = fmaf(w.w, v, acc[e0 * 4 + 3]);
        }
    }
    float4* outp = (float4*)(g_feat0 + ((size_t)(b * NN + n)) * FE);
    #pragma unroll
    for (int e0 = 0; e0 < 8; ++e0)
        outp[e0] = make_float4(acc[e0 * 4 + 0], acc[e0 * 4 + 1], acc[e0 * 4 + 2], acc[e0 * 4 + 3]);
}

// ---------------- kernel 3: autonomous-wave z-windowed KNN ---------------
// FROZEN reference arithmetic (verified R5):
//   dot  = fma(zq,zm, fma(yq,ym, xq*xm))
//   dist = fadd( fma(-2, dot, xx_q), xx_m )
// One wave owns 8 z-adjacent queries; no __syncthreads, no LDS atomics.
// Exactness: accept iff 16 <= cnt <= CAPQ (stack then holds ALL gate
// passers; z-window [zq-R,zq+R], R=sqrt(t0+1e-3)+1e-3 (+-1 bin) covers the
// gate set). Threshold search: bracketed geometric bisection (R12-proven;
// terminates even for bit-equal d16==d17 since a 15->17 count jump lands
// inside [16,64]). Selection: COUNTING-RANK -- each lane ranks its stack
// element by counting strictly-smaller u64 keys (LDS broadcast reads, no
// serial shuffle chain; keys unique since idx is in the low bits); ranks
// 0..15 are exactly the lexicographic (dist,idx) top-16.
__global__ __launch_bounds__(256) void k_knn() {
    __shared__ unsigned long long qbuf[WPB * QPW * CAPQ];   // 16 KB
    int tid = threadIdx.x;
    int lane = tid & 63;
    int w = tid >> 6;
    int wid = blockIdx.x * WPB + w;             // 0..8191
    int b = wid >> 10;                          // 1024 waves per batch
    int n0 = (wid & 1023) * QPW;
    const float4* S = g_sorted + (size_t)b * NN;
    const int* SO = g_sorig + (size_t)b * NN;
    const unsigned* BO = g_binoff + b * (ZBINS + 1);
    unsigned long long lt = (1ull << lane) - 1ull;

    float qx[QPW], qy[QPW], qz[QPW], qxx[QPW], t0[QPW], tlo[QPW], thi[QPW];
    int qorig[QPW];
    unsigned cnt[QPW];
    bool qdone[QPW];
    #pragma unroll
    for (int i = 0; i < QPW; ++i) {
        float4 qv = S[n0 + i];
        qx[i] = qv.x; qy[i] = qv.y; qz[i] = qv.z; qxx[i] = qv.w;
        qorig[i] = SO[n0 + i];
        float tt = 0.053f * __expf(qxx[i] * (1.0f / 3.0f));  // ~32 expected passers
        t0[i] = tt > 3.f ? 3.f : tt;
        tlo[i] = 0.f; thi[i] = 0.f;             // 0 = unset bracket ends
        cnt[i] = 0;
        qdone[i] = false;
    }

    for (int attempt = 0; attempt < 40; ++attempt) {
        // wave-private window over active queries (uniform arithmetic)
        float zlo = 1e30f, zhi = -1e30f;
        bool anyact = false;
        #pragma unroll
        for (int i = 0; i < QPW; ++i) {
            if (qdone[i]) continue;
            anyact = true;
            float R = __fsqrt_rn(t0[i] + 1e-3f) + 1e-3f;
            zlo = fminf(zlo, qz[i] - R);
            zhi = fmaxf(zhi, qz[i] + R);
        }
        if (!anyact) break;
        int blo = zbin(zlo) - 1; if (blo < 0) blo = 0;
        int bhi = zbin(zhi) + 1; if (bhi > ZBINS - 1) bhi = ZBINS - 1;
        int lo = (int)BO[blo];
        int hi = (int)BO[bhi + 1];

        for (int p = lo; p < hi; p += 64) {
            int jj = p + lane;
            int j = jj < hi ? jj : hi - 1;
            float4 cc = S[j];
            int corig = SO[j];
            unsigned long long inbm = __ballot(jj < hi);
            #pragma unroll
            for (int i = 0; i < QPW; ++i) {
                if (qdone[i]) continue;                       // uniform branch
                float dot = __fmaf_rn(qz[i], cc.z, __fmaf_rn(qy[i], cc.y, __fmul_rn(qx[i], cc.x)));
                float dist = __fadd_rn(__fmaf_rn(-2.f, dot, qxx[i]), cc.w);
                unsigned long long mask = __ballot(dist <= t0[i]) & inbm;
                if (mask) {
                    bool pr = (dist <= t0[i]) && (jj < hi);
                    unsigned pos = cnt[i] + (unsigned)__popcll(mask & lt);
                    if (pr && pos < CAPQ) {
                        int db = __float_as_int(dist);
                        unsigned key = (unsigned)db ^ (unsigned)((db >> 31) | 0x80000000);
                        qbuf[(w * QPW + i) * CAPQ + pos] =
                            ((unsigned long long)key << 32) | (unsigned)corig;
                    }
                    cnt[i] += (unsigned)__popcll(mask);
                }
            }
        }
        #pragma unroll
        for (int i = 0; i < QPW; ++i) {
            if (qdone[i]) continue;
            if (cnt[i] < KN) {
                tlo[i] = t0[i];
                t0[i] = (thi[i] > 0.f) ? __fsqrt_rn(tlo[i] * thi[i]) : t0[i] * 2.0f;
                cnt[i] = 0;
            } else if (cnt[i] > CAPQ) {
                thi[i] = t0[i];
                t0[i] = (tlo[i] > 0.f) ? __fsqrt_rn(tlo[i] * thi[i]) : t0[i] * 0.5f;
                cnt[i] = 0;
            } else {
                qdone[i] = true; t0[i] = -1.0e30f;           // freeze stack
            }
        }
    }

    // ---- selection: counting-rank over the stack (no shuffle chains) ----
    #pragma unroll
    for (int i = 0; i < QPW; ++i) {
        unsigned tot = cnt[i] > CAPQ ? CAPQ : cnt[i];
        const unsigned long long* pb = qbuf + (w * QPW + i) * CAPQ;
        unsigned long long e0 = ((unsigned)lane < tot) ? pb[lane] : ~0ull;
        unsigned rank0 = 0;
        for (unsigned j = 0; j < tot; ++j) {
            unsigned long long v = pb[j];       // uniform addr -> LDS broadcast
            rank0 += (v < e0) ? 1u : 0u;
        }
        int obase = (b * NN + qorig[i]) * KN;
        if (((unsigned)lane < tot) && rank0 < KN)
            g_idx[obase + rank0] = (int)(e0 & 0xffffffffull);
    }
}

// ---------------- kernel 4: gather+max, rel, out = Wh' * rel ----------------
__global__ __launch_bounds__(256) void k_out(const float* __restrict__ Wh,
        float* __restrict__ out) {
    __shared__ float whs[CC * FE];
    int tid = threadIdx.x;
    for (int i = tid; i < CC * FE; i += 256) {
        int c = i >> 5, e = i & 31;
        float s = 0.f;
        #pragma unroll
        for (int m = 0; m < 4; ++m) s += Wh[c * 128 + m * 32 + e];
        whs[i] = s;
    }
    __syncthreads();
    int b = blockIdx.x >> 5;
    int n = ((blockIdx.x & 31) << 8) + tid;
    const int* ip = g_idx + (size_t)(b * NN + n) * KN;
    const float4* f0 = (const float4*)(g_feat0 + (size_t)b * NN * FE);
    float gmax[FE];
    #pragma unroll
    for (int e = 0; e < FE; ++e) gmax[e] = -__builtin_inff();
    for (int k = 0; k < KN; ++k) {
        int id = ip[k] & (NN - 1);      // defensive mask, no-op for valid idx
        const float4* row = f0 + (size_t)id * 8;
        #pragma unroll
        for (int e0 = 0; e0 < 8; ++e0) {
            float4 v = row[e0];
            gmax[e0 * 4 + 0] = fmaxf(gmax[e0 * 4 + 0], v.x);
            gmax[e0 * 4 + 1] = fmaxf(gmax[e0 * 4 + 1], v.y);
            gmax[e0 * 4 + 2] = fmaxf(gmax[e0 * 4 + 2], v.z);
            gmax[e0 * 4 + 3] = fmaxf(gmax[e0 * 4 + 3], v.w);
        }
    }
    const float4* selfr = f0 + (size_t)n * 8;
    float rel[FE];
    #pragma unroll
    for (int e0 = 0; e0 < 8; ++e0) {
        float4 v = selfr[e0];
        rel[e0 * 4 + 0] = gmax[e0 * 4 + 0] - v.x;
        rel[e0 * 4 + 1] = gmax[e0 * 4 + 1] - v.y;
        rel[e0 * 4 + 2] = gmax[e0 * 4 + 2] - v.z;
        rel[e0 * 4 + 3] = gmax[e0 * 4 + 3] - v.w;
    }
    float* op = out + (size_t)b * CC * NN + n;
    for (int c = 0; c < CC; ++c) {
        const float4* w4 = (const float4*)(whs + c * FE);
        float s = 0.f;
        #pragma unroll
        for (int e0 = 0; e0 < 8; ++e0) {
            float4 w = w4[e0];
            s = fmaf(w.x, rel[e0 * 4 + 0], s);
            s = fmaf(w.y, rel[e0 * 4 + 1], s);
            s = fmaf(w.z, rel[e0 * 4 + 2], s);
            s = fmaf(w.w, rel[e0 * 4 + 3], s);
        }
        op[(size_t)c * NN] = s;
    }
}

extern "C" void kernel_launch(void* const* d_in, const int* in_sizes, int n_in,
                              void* d_out, int out_size, void* d_ws, size_t ws_size,
                              hipStream_t stream) {
    const float* xyz   = (const float*)d_in[0];
    const float* feat  = (const float*)d_in[1];
    const float* gamma = (const float*)d_in[2];
    const float* beta  = (const float*)d_in[3];
    const float* Wg    = (const float*)d_in[4];
    const float* Wh    = (const float*)d_in[5];
    float* out = (float*)d_out;
    (void)d_ws; (void)ws_size;

    hipLaunchKernelGGL(k_bnstats, dim3(64),   dim3(1024), 0, stream, feat, gamma, beta);
    hipLaunchKernelGGL(k_zbin,    dim3(8),    dim3(1024), 0, stream, xyz);
    hipLaunchKernelGGL(k_feat0,   dim3(256),  dim3(256),  0, stream, feat, xyz, Wg);
    hipLaunchKernelGGL(k_knn,     dim3(2048), dim3(256),  0, stream);
    hipLaunchKernelGGL(k_out,     dim3(256),  dim3(256),  0, stream, Wh, out);
}